// Round 14
// baseline (285.244 us; speedup 1.0000x reference)
//
#include <hip/hip_runtime.h>
#include <hip/hip_bf16.h>
#include <math.h>

#define TN 201
#define NSTEP 200
#define BATCH 4096
#define DIM 20
#define HID 128

typedef __attribute__((ext_vector_type(8))) short short8;
typedef __attribute__((ext_vector_type(4))) short sv4;  // NOT "short4": HIP defines that type
typedef __attribute__((ext_vector_type(4))) float f32x4;

union S8U { short8 s; unsigned u[4]; };
union S4U { sv4 s; unsigned u[2]; };

__device__ __forceinline__ unsigned pk2(float lo, float hi) {
  __hip_bfloat162 h = __float22bfloat162_rn(make_float2(lo, hi));
  union { __hip_bfloat162 h; unsigned u; } v;
  v.h = h;
  return v.u;
}
__device__ __forceinline__ float tanh_fast(float x) {
  float e = __builtin_amdgcn_exp2f(x * 2.8853900817779268f);
  return 1.f - 2.f * __builtin_amdgcn_rcpf(e + 1.f);
}

#define MFMA32(a, b, c) __builtin_amdgcn_mfma_f32_16x16x32_bf16((a), (b), (c), 0, 0, 0)

// 16x16x16 bf16 MFMA (A/B = 4 bf16 = 2 VGPRs).
#if defined(__has_builtin)
#if __has_builtin(__builtin_amdgcn_mfma_f32_16x16x16bf16_1k)
#define MFMA16K(a, b, c) __builtin_amdgcn_mfma_f32_16x16x16bf16_1k((a), (b), (c), 0, 0, 0)
#endif
#endif
#ifndef MFMA16K
__device__ __forceinline__ f32x4 mfma16k_asm(sv4 a, sv4 b, f32x4 c) {
  f32x4 d;
  asm volatile("v_mfma_f32_16x16x16_bf16 %0, %1, %2, %3"
               : "=v"(d) : "v"(a), "v"(b), "v"(c));
  return d;
}
#define MFMA16K(a, b, c) mfma16k_asm((a), (b), (c))
#endif

// ws layout (floats):
//   [0..399]       Pp  = sigma^T P        (Pp[d][k])
//   [400..799]     Mp  = -sigma^T A sigma^{-T}
//   [800..1199]    Qp  = sigma^T Q
//   [1200..1399]   dt[200]
//   [1400..1599]   1/sqrt(dt)[200]
//   [1600..1631]   b2p = sigma^T b2 (padded to 32, zeros beyond 20)
//   [2048..4607]   W2p = W2 sigma  [128][20]
//   [5120..7167]   W1TF: 8 frags x 64 lanes x 4 dw  (A-frag, layer1^T)
//   [7168..9215]   W2PTF: 16 frags x 64 lanes x 2 dw (A-frag, layer2^T 16x16x16)
//   [9216..9727]   PPTF: 2 tiles x 64 x 4 dw
//   [9728..10239]  MPTF: 2 tiles x 64 x 4 dw
//   [12288 ...]    zc: A1[nch][81920], A2[nch][81920], S[nch][81920]

// ================= k0: setup =================
__global__ __launch_bounds__(256) void k0_setup(
    const float* __restrict__ ts, const float* __restrict__ sigma,
    const float* __restrict__ A, const float* __restrict__ P,
    const float* __restrict__ Q, const float* __restrict__ W2,
    const float* __restrict__ b2, const float* __restrict__ W1,
    const float* __restrict__ b1, float* __restrict__ wsc) {
  __shared__ float aug[20][40];
  __shared__ float sS[400], sA[400], sT1[400];
  __shared__ float fac[20];
  int tid = threadIdx.x;
  for (int e = tid; e < 400; e += 256) { sS[e] = sigma[e]; sA[e] = A[e]; }
  for (int e = tid; e < 800; e += 256) {
    int i = e / 40, j = e % 40;
    aug[i][j] = (j < 20) ? sigma[i * 20 + j] : ((j - 20) == i ? 1.f : 0.f);
  }
  __syncthreads();
  for (int p = 0; p < 20; ++p) {
    if (tid < 64) {
      float pv = aug[p][p];
      float r = 1.f / pv;
      float rowv = 0.f, facv = 0.f;
      if (tid < 40) rowv = aug[p][tid];
      if (tid >= 40 && tid < 60) facv = aug[tid - 40][p];
      if (tid < 40) aug[p][tid] = rowv * r;
      if (tid >= 40 && tid < 60) fac[tid - 40] = facv;
    }
    __syncthreads();
    for (int e = tid; e < 800; e += 256) {
      int i = e / 40, j = e % 40;
      if (i != p) aug[i][j] -= fac[i] * aug[p][j];
    }
    __syncthreads();
  }
  // T1[k][j] = (A sigma^{-T})[k][j]
  for (int e = tid; e < 400; e += 256) {
    int k = e / 20, j = e % 20;
    float s = 0.f;
    for (int l2 = 0; l2 < 20; ++l2) s += sA[k * 20 + l2] * aug[j][20 + l2];
    sT1[e] = s;
  }
  __syncthreads();
  for (int e = tid; e < 400; e += 256) {
    int i = e / 20, j = e % 20;
    float m = 0.f, pp = 0.f, qq = 0.f;
    for (int k = 0; k < 20; ++k) {
      float sk = sS[k * 20 + i];
      m += sk * sT1[k * 20 + j];
      pp += sk * P[k * 20 + j];
      qq += sk * Q[k * 20 + j];
    }
    wsc[e] = pp;
    wsc[400 + e] = -m;
    wsc[800 + e] = qq;
  }
  for (int e = tid; e < 2560; e += 256) {
    int h = e / 20, i = e % 20;
    float s = 0.f;
    for (int j = 0; j < 20; ++j) s += W2[h * 20 + j] * sS[j * 20 + i];
    wsc[2048 + e] = s;
  }
  if (tid < 32) {
    float s = 0.f;
    if (tid < 20)
      for (int j = 0; j < 20; ++j) s += b2[j] * sS[j * 20 + tid];
    wsc[1600 + tid] = s;
  }
  if (tid < NSTEP) {
    float d = ts[tid + 1] - ts[tid];
    wsc[1200 + tid] = d;
    wsc[1400 + tid] = rsqrtf(d);
  }
  __syncthreads();

  unsigned* wu = (unsigned*)wsc;
  // W1TF (layer1^T A-frag): lane(quad,m16), n = nt*16+m16, k = quad*8+j
  for (int e = tid; e < 2048; e += 256) {
    int nt = e >> 8, rem = e & 255, l = rem >> 2, jj = rem & 3;
    int quad = l >> 4, m16 = l & 15;
    int n = nt * 16 + m16;
    int k0 = quad * 8 + 2 * jj;
    auto wf = [&](int k) -> float {
      if (k < 20) return W1[(k + 1) * HID + n];
      if (k == 20) return W1[n];       // t row
      if (k == 21) return b1[n];       // bias column (X supplies 1.0)
      return 0.f;
    };
    wu[5120 + e] = pk2(wf(k0), wf(k0 + 1));
  }
  // W2PTF (layer2^T 16x16x16 A-frags): frag f = hk*2+tile; 2 dw/lane
  for (int e = tid; e < 2048; e += 256) {
    int f = e >> 7, rem = e & 127, l = rem >> 1, jj = rem & 1;
    int hk = f >> 1, tile = f & 1;
    int m16 = l & 15;
    int quad = l >> 4;
    int d = tile ? 16 + m16 : m16;
    bool ok = (d < 20);
    int h0 = hk * 16 + quad * 4 + 2 * jj;
    float f0 = ok ? wsc[2048 + h0 * 20 + d] : 0.f;
    float f1 = ok ? wsc[2048 + (h0 + 1) * 20 + d] : 0.f;
    wu[7168 + e] = pk2(f0, f1);
  }
  // PPTF / MPTF (integrand^T A-frags, K=32 layout): tile in {0,1}
  for (int e = tid; e < 512; e += 256) {
    int tile = e >> 8, rem = e & 255, l = rem >> 2, jj = rem & 3;
    int quad = l >> 4, m16 = l & 15;
    int d = tile ? 16 + m16 : m16;
    bool ok = (d < 20);
    int k0 = quad * 8 + 2 * jj;
    float f0 = (ok && k0 < 20) ? wsc[d * 20 + k0] : 0.f;
    float f1 = (ok && k0 + 1 < 20) ? wsc[d * 20 + k0 + 1] : 0.f;
    wu[9216 + e] = pk2(f0, f1);
    float g0 = (ok && k0 < 20) ? wsc[400 + d * 20 + k0] : 0.f;
    float g1 = (ok && k0 + 1 < 20) ? wsc[400 + d * 20 + k0 + 1] : 0.f;
    wu[9728 + e] = pk2(g0, g1);
  }
}

// ================= kernel A: fully-transposed MLP scan, ZERO LDS =================
// r13 post-mortem: mixed latency/issue-bound at 2 waves/SIMD (issue ~50%).
// This round buys the 3rd wave/SIMD by dropping the n/c prefetch registers
// (-16 regs: 184 -> 168 <= (256,3)'s 170 budget). n/c are consumed only in
// the integrand ~2/3 into the ~7600-cycle body, so in-iteration loads (issued
// at body top) hide HBM latency without rotation registers. x keeps the
// one-ahead prefetch (consumed immediately); scalars rotate in SGPRs.
// Canaries: FETCH >> 130 MB = spill (revert to (256,2)); LDS must stay 0.
__global__ __launch_bounds__(256, 3) void kA(
    const float* __restrict__ states, const float* __restrict__ noises,
    const float* __restrict__ controls, const float* __restrict__ ts,
    const float* __restrict__ wsc, float* __restrict__ zc,
    int nch, int cbase, int crem) {
  const int tid = threadIdx.x;
  const int l = tid & 63;
  const int w = tid >> 6;
  const int quad = l >> 4;
  const int m16 = l & 15;

  const int c = blockIdx.x >> 6;
  const int slab = blockIdx.x & 63;
  const int b0 = slab * 64 + w * 16;
  const int sz = cbase + ((c < crem) ? 1 : 0);
  const int thi = 200 - (c * cbase + ((c < crem) ? c : crem));
  const int tlo = thi - (sz - 1);

  // ---- weight fragments (coalesced loads from prepacked tables) ----
  short8 W1T[8];
#pragma unroll
  for (int nt = 0; nt < 8; ++nt)
    W1T[nt] = *(const short8*)(wsc + 5120 + nt * 256 + l * 4);
  sv4 W2T[16];
#pragma unroll
  for (int f = 0; f < 16; ++f)
    W2T[f] = *(const sv4*)(wsc + 7168 + f * 128 + l * 2);
  const short8 PPT0 = *(const short8*)(wsc + 9216 + l * 4);
  const short8 PPT1 = *(const short8*)(wsc + 9472 + l * 4);
  const short8 MPT0 = *(const short8*)(wsc + 9728 + l * 4);
  const short8 MPT1 = *(const short8*)(wsc + 9984 + l * 4);
  const f32x4 b2Av = *(const f32x4*)(wsc + 1600 + quad * 4);
  const f32x4 b2Bv = *(const f32x4*)(wsc + 1616 + quad * 4);

  // ---- global pointers (16B-aligned per-quad slices) ----
  const int row20 = (b0 + m16) * 20;
  const int qoff = (quad == 0) ? 0 : ((quad == 1) ? 8 : 12);
  const float* gx = states + row20 + qoff;
  const float* gn = noises + row20 + qoff;
  const float* gc = controls + row20 + qoff;

  // ---- scan accumulators (tile0: d=quad*4+reg; tile1: d=16+reg, quad0 only) ----
  f32x4 A1a = {0.f, 0.f, 0.f, 0.f}, A1b = {0.f, 0.f, 0.f, 0.f};
  f32x4 A2a = {0.f, 0.f, 0.f, 0.f}, A2b = {0.f, 0.f, 0.f, 0.f};
  f32x4 La = {0.f, 0.f, 0.f, 0.f}, Lb = {0.f, 0.f, 0.f, 0.f};

  // ---- preload first t: x (vector) + scalars; n/c are loaded in-iteration ----
  float4 xv0, xv1;
  float tval, dtv = 0.f, rsd = 0.f;
  {
    size_t rb = (size_t)thi * (BATCH * 20);
    xv0 = *(const float4*)(gx + rb);
    xv1 = *(const float4*)(gx + rb + 4);
    tval = ts[thi];
    if (thi < 200) { dtv = wsc[1200 + thi]; rsd = wsc[1400 + thi]; }
  }

#pragma unroll 1
  for (int t = thi; t >= tlo; --t) {
    const bool has_s = (t < 200);
    // ---- in-iteration n/c loads for CURRENT t (consumed in integrand,
    //      ~2/3 into the body -> latency hidden without prefetch regs) ----
    float4 nv0 = {0, 0, 0, 0}, nv1 = {0, 0, 0, 0};
    float4 cv0 = {0, 0, 0, 0}, cv1 = {0, 0, 0, 0};
    if (has_s) {
      size_t rb = (size_t)t * (BATCH * 20);
      nv0 = *(const float4*)(gn + rb); nv1 = *(const float4*)(gn + rb + 4);
      cv0 = *(const float4*)(gc + rb); cv1 = *(const float4*)(gc + rb + 4);
    }
    // ---- x/scalar prefetch for t-1 ----
    float4 xn0, xn1;
    float tvn, dtn, rsn;
    if (t > tlo) {
      size_t rb = (size_t)(t - 1) * (BATCH * 20);
      xn0 = *(const float4*)(gx + rb); xn1 = *(const float4*)(gx + rb + 4);
      tvn = ts[t - 1];
      dtn = wsc[1200 + t - 1]; rsn = wsc[1400 + t - 1];
    }

    // ---- X^T B-fragment (K order: x0..x19, t@20, 1.0@21) ----
    S8U af;
    if (quad <= 1) {
      af.u[0] = pk2(xv0.x, xv0.y); af.u[1] = pk2(xv0.z, xv0.w);
      af.u[2] = pk2(xv1.x, xv1.y); af.u[3] = pk2(xv1.z, xv1.w);
    } else if (quad == 2) {        // loads were x[12..19]
      af.u[0] = pk2(xv1.x, xv1.y); af.u[1] = pk2(xv1.z, xv1.w);
      af.u[2] = pk2(tval, 1.0f);   af.u[3] = 0u;
    } else {
      af.u[0] = af.u[1] = af.u[2] = af.u[3] = 0u;
    }
    const short8 afs = af.s;

    const f32x4 z4 = {0.f, 0.f, 0.f, 0.f};
    // ---- layer1^T: 8 independent MFMAs -> lane holds H^T[16nt+quad*4+reg][m16]
    f32x4 h0 = MFMA32(W1T[0], afs, z4);
    f32x4 h1 = MFMA32(W1T[1], afs, z4);
    f32x4 h2 = MFMA32(W1T[2], afs, z4);
    f32x4 h3 = MFMA32(W1T[3], afs, z4);
    f32x4 h4 = MFMA32(W1T[4], afs, z4);
    f32x4 h5 = MFMA32(W1T[5], afs, z4);
    f32x4 h6 = MFMA32(W1T[6], afs, z4);
    f32x4 h7 = MFMA32(W1T[7], afs, z4);

    // ---- layer2^T: tanh in regs -> 16x16x16 MFMAs, no lane permutation ----
    f32x4 u0 = b2Av, u1 = b2Bv;
#define L2STEP(hk, hr)                                                  \
    {                                                                   \
      S4U hb;                                                           \
      hb.u[0] = pk2(tanh_fast(hr[0]), tanh_fast(hr[1]));                \
      hb.u[1] = pk2(tanh_fast(hr[2]), tanh_fast(hr[3]));                \
      u0 = MFMA16K(W2T[2 * hk], hb.s, u0);                              \
      u1 = MFMA16K(W2T[2 * hk + 1], hb.s, u1);                          \
    }
    L2STEP(0, h0) L2STEP(1, h1) L2STEP(2, h2) L2STEP(3, h3)
    L2STEP(4, h4) L2STEP(5, h5) L2STEP(6, h6) L2STEP(7, h7)
#undef L2STEP

    // ---- integrand^T: S^T = Pp.X^T + Mp.Y^T (X frag reused) ----
    f32x4 s0 = z4, s1 = z4;
    if (has_s) {
      S8U yf;
      if (quad <= 1) {
        yf.u[0] = pk2(fmaf(nv0.x, rsd, cv0.x), fmaf(nv0.y, rsd, cv0.y));
        yf.u[1] = pk2(fmaf(nv0.z, rsd, cv0.z), fmaf(nv0.w, rsd, cv0.w));
        yf.u[2] = pk2(fmaf(nv1.x, rsd, cv1.x), fmaf(nv1.y, rsd, cv1.y));
        yf.u[3] = pk2(fmaf(nv1.z, rsd, cv1.z), fmaf(nv1.w, rsd, cv1.w));
      } else if (quad == 2) {
        yf.u[0] = pk2(fmaf(nv1.x, rsd, cv1.x), fmaf(nv1.y, rsd, cv1.y));
        yf.u[1] = pk2(fmaf(nv1.z, rsd, cv1.z), fmaf(nv1.w, rsd, cv1.w));
        yf.u[2] = 0u; yf.u[3] = 0u;
      } else {
        yf.u[0] = yf.u[1] = yf.u[2] = yf.u[3] = 0u;
      }
      f32x4 a0 = MFMA32(PPT0, afs, z4);
      a0 = MFMA32(MPT0, yf.s, a0);
      f32x4 a1 = MFMA32(PPT1, afs, z4);
      a1 = MFMA32(MPT1, yf.s, a1);
      s0 = a0 * dtv;
      s1 = a1 * dtv;
    }

    // ---- scan update ----
    La += s0;
    Lb += s1;
    f32x4 p0 = u0 - La;
    f32x4 p1 = u1 - Lb;
    A2a += p0;
    A2b += p1;
    A1a += p0 * p0;
    A1b += p1 * p1;

    // rotate prefetch (x + scalars only)
    xv0 = xn0; xv1 = xn1;
    tval = tvn; dtv = dtn; rsd = rsn;
  }

  // ---- epilogue: lane owns batch b0+m16, dims quad*4+reg (+16.. for quad0) ----
  const size_t CH = (size_t)BATCH * DIM;
  float* zA1 = zc;
  float* zA2 = zc + (size_t)nch * CH;
  float* zS = zc + (size_t)2 * nch * CH;
  size_t base = ((size_t)c * BATCH + (b0 + m16)) * 20 + quad * 4;
#pragma unroll
  for (int reg = 0; reg < 4; ++reg) {
    zA1[base + reg] = A1a[reg];
    zA2[base + reg] = A2a[reg];
    zS[base + reg] = La[reg];
  }
  if (quad == 0) {
#pragma unroll
    for (int reg = 0; reg < 4; ++reg) {
      zA1[base + 16 + reg] = A1b[reg];
      zA2[base + 16 + reg] = A2b[reg];
      zS[base + 16 + reg] = Lb[reg];
    }
  }
}

// ================= kernel B: combine chunks =================
__global__ __launch_bounds__(256) void kB(
    const float* __restrict__ states, const float* __restrict__ lw,
    const float* __restrict__ wsc, const float* __restrict__ zc,
    float* __restrict__ out, int nch, int cbase, int crem) {
  __shared__ float sQp[400];
  __shared__ float part[4];
  int tid = threadIdx.x;
  for (int e = tid; e < 400; e += 256) sQp[e] = wsc[800 + e];
  __syncthreads();
  const int u = blockIdx.x * 256 + tid;
  const int b = u / 20;
  const int i = u - b * 20;
  const float* xp = states + ((size_t)NSTEP * BATCH + b) * 20;
  float term = 0.f;
#pragma unroll
  for (int j = 0; j < 20; ++j) term = fmaf(sQp[i * 20 + j], xp[j], term);

  const size_t CH = (size_t)BATCH * DIM;
  float T = 0.f, obj = 0.f;
  for (int c = 0; c < nch; ++c) {
    float A1 = zc[(size_t)c * CH + u];
    float A2 = zc[(size_t)(nch + c) * CH + u];
    float S = zc[(size_t)(2 * nch + c) * CH + u];
    float K = term + T;
    float nc = (float)(cbase + ((c < crem) ? 1 : 0));
    obj += A1 - 2.f * K * A2 + nc * K * K;
    T += S;
  }
  obj *= __expf(lw[b]) * (1.f / ((float)TN * (float)BATCH));
#pragma unroll
  for (int off = 32; off > 0; off >>= 1) obj += __shfl_down(obj, off, 64);
  if ((tid & 63) == 0) part[tid >> 6] = obj;
  __syncthreads();
  if (tid == 0) atomicAdd(out, (part[0] + part[1]) + (part[2] + part[3]));
}

extern "C" void kernel_launch(void* const* d_in, const int* in_sizes, int n_in,
                              void* d_out, int out_size, void* d_ws, size_t ws_size,
                              hipStream_t stream) {
  const float* states = (const float*)d_in[0];
  const float* noises = (const float*)d_in[1];
  const float* controls = (const float*)d_in[2];
  const float* lw = (const float*)d_in[3];
  const float* ts = (const float*)d_in[4];
  const float* sigma = (const float*)d_in[5];
  const float* P = (const float*)d_in[6];
  const float* A = (const float*)d_in[7];
  const float* Q = (const float*)d_in[8];
  const float* W1 = (const float*)d_in[9];
  const float* b1 = (const float*)d_in[10];
  const float* W2 = (const float*)d_in[11];
  const float* b2 = (const float*)d_in[12];
  float* out = (float*)d_out;

  float* wsc = (float*)d_ws;
  float* zc = wsc + 12288;

  // nch=12 -> 768 blocks = exactly 3 blocks/CU, matching the (256,3)
  // 3-waves/SIMD residency this round's register diet enables.
  int nch = 12;
  size_t need = ((size_t)12288 + (size_t)3 * nch * BATCH * DIM) * sizeof(float);
  if (ws_size < need) nch = 8;
  int cbase = TN / nch;
  int crem = TN - cbase * nch;

  (void)hipMemsetAsync(out, 0, sizeof(float), stream);
  hipLaunchKernelGGL(k0_setup, dim3(1), dim3(256), 0, stream,
                     ts, sigma, A, P, Q, W2, b2, W1, b1, wsc);
  hipLaunchKernelGGL(kA, dim3(nch * 64), dim3(256), 0, stream,
                     states, noises, controls, ts, wsc, zc, nch, cbase, crem);
  hipLaunchKernelGGL(kB, dim3((BATCH * DIM) / 256), dim3(256), 0, stream,
                     states, lw, wsc, zc, out, nch, cbase, crem);
}

// Round 15
// 262.819 us; speedup vs baseline: 1.0853x; 1.0853x over previous
//
#include <hip/hip_runtime.h>
#include <hip/hip_bf16.h>
#include <math.h>

#define TN 201
#define NSTEP 200
#define BATCH 4096
#define DIM 20
#define HID 128

typedef __attribute__((ext_vector_type(8))) short short8;
typedef __attribute__((ext_vector_type(4))) short sv4;  // NOT "short4": HIP defines that type
typedef __attribute__((ext_vector_type(4))) float f32x4;

union S8U { short8 s; unsigned u[4]; };
union S4U { sv4 s; unsigned u[2]; };

__device__ __forceinline__ unsigned pk2(float lo, float hi) {
  __hip_bfloat162 h = __float22bfloat162_rn(make_float2(lo, hi));
  union { __hip_bfloat162 h; unsigned u; } v;
  v.h = h;
  return v.u;
}
__device__ __forceinline__ float tanh_fast(float x) {
  float e = __builtin_amdgcn_exp2f(x * 2.8853900817779268f);
  return 1.f - 2.f * __builtin_amdgcn_rcpf(e + 1.f);
}

#define MFMA32(a, b, c) __builtin_amdgcn_mfma_f32_16x16x32_bf16((a), (b), (c), 0, 0, 0)

// 16x16x16 bf16 MFMA (A/B = 4 bf16 = 2 VGPRs).
#if defined(__has_builtin)
#if __has_builtin(__builtin_amdgcn_mfma_f32_16x16x16bf16_1k)
#define MFMA16K(a, b, c) __builtin_amdgcn_mfma_f32_16x16x16bf16_1k((a), (b), (c), 0, 0, 0)
#endif
#endif
#ifndef MFMA16K
__device__ __forceinline__ f32x4 mfma16k_asm(sv4 a, sv4 b, f32x4 c) {
  f32x4 d;
  asm volatile("v_mfma_f32_16x16x16_bf16 %0, %1, %2, %3"
               : "=v"(d) : "v"(a), "v"(b), "v"(c));
  return d;
}
#define MFMA16K(a, b, c) mfma16k_asm((a), (b), (c))
#endif

// ws layout (floats):
//   [0..399]       Pp  = sigma^T P        (Pp[d][k])
//   [400..799]     Mp  = -sigma^T A sigma^{-T}
//   [800..1199]    Qp  = sigma^T Q
//   [1200..1399]   dt[200]
//   [1400..1599]   1/sqrt(dt)[200]
//   [1600..1631]   b2p = sigma^T b2 (padded to 32, zeros beyond 20)
//   [2048..4607]   W2p = W2 sigma  [128][20]
//   [5120..7167]   W1TF: 8 frags x 64 lanes x 4 dw  (A-frag, layer1^T)
//   [7168..9215]   W2PTF: 16 frags x 64 lanes x 2 dw (A-frag, layer2^T 16x16x16)
//   [9216..9727]   PPTF: 2 tiles x 64 x 4 dw
//   [9728..10239]  MPTF: 2 tiles x 64 x 4 dw
//   [12288 ...]    zc: A1[nch][81920], A2[nch][81920], S[nch][81920]

// ================= k0: setup =================
__global__ __launch_bounds__(256) void k0_setup(
    const float* __restrict__ ts, const float* __restrict__ sigma,
    const float* __restrict__ A, const float* __restrict__ P,
    const float* __restrict__ Q, const float* __restrict__ W2,
    const float* __restrict__ b2, const float* __restrict__ W1,
    const float* __restrict__ b1, float* __restrict__ wsc) {
  __shared__ float aug[20][40];
  __shared__ float sS[400], sA[400], sT1[400];
  __shared__ float fac[20];
  int tid = threadIdx.x;
  for (int e = tid; e < 400; e += 256) { sS[e] = sigma[e]; sA[e] = A[e]; }
  for (int e = tid; e < 800; e += 256) {
    int i = e / 40, j = e % 40;
    aug[i][j] = (j < 20) ? sigma[i * 20 + j] : ((j - 20) == i ? 1.f : 0.f);
  }
  __syncthreads();
  for (int p = 0; p < 20; ++p) {
    if (tid < 64) {
      float pv = aug[p][p];
      float r = 1.f / pv;
      float rowv = 0.f, facv = 0.f;
      if (tid < 40) rowv = aug[p][tid];
      if (tid >= 40 && tid < 60) facv = aug[tid - 40][p];
      if (tid < 40) aug[p][tid] = rowv * r;
      if (tid >= 40 && tid < 60) fac[tid - 40] = facv;
    }
    __syncthreads();
    for (int e = tid; e < 800; e += 256) {
      int i = e / 40, j = e % 40;
      if (i != p) aug[i][j] -= fac[i] * aug[p][j];
    }
    __syncthreads();
  }
  // T1[k][j] = (A sigma^{-T})[k][j]
  for (int e = tid; e < 400; e += 256) {
    int k = e / 20, j = e % 20;
    float s = 0.f;
    for (int l2 = 0; l2 < 20; ++l2) s += sA[k * 20 + l2] * aug[j][20 + l2];
    sT1[e] = s;
  }
  __syncthreads();
  for (int e = tid; e < 400; e += 256) {
    int i = e / 20, j = e % 20;
    float m = 0.f, pp = 0.f, qq = 0.f;
    for (int k = 0; k < 20; ++k) {
      float sk = sS[k * 20 + i];
      m += sk * sT1[k * 20 + j];
      pp += sk * P[k * 20 + j];
      qq += sk * Q[k * 20 + j];
    }
    wsc[e] = pp;
    wsc[400 + e] = -m;
    wsc[800 + e] = qq;
  }
  for (int e = tid; e < 2560; e += 256) {
    int h = e / 20, i = e % 20;
    float s = 0.f;
    for (int j = 0; j < 20; ++j) s += W2[h * 20 + j] * sS[j * 20 + i];
    wsc[2048 + e] = s;
  }
  if (tid < 32) {
    float s = 0.f;
    if (tid < 20)
      for (int j = 0; j < 20; ++j) s += b2[j] * sS[j * 20 + tid];
    wsc[1600 + tid] = s;
  }
  if (tid < NSTEP) {
    float d = ts[tid + 1] - ts[tid];
    wsc[1200 + tid] = d;
    wsc[1400 + tid] = rsqrtf(d);
  }
  __syncthreads();

  unsigned* wu = (unsigned*)wsc;
  // W1TF (layer1^T A-frag): lane(quad,m16), n = nt*16+m16, k = quad*8+j
  for (int e = tid; e < 2048; e += 256) {
    int nt = e >> 8, rem = e & 255, l = rem >> 2, jj = rem & 3;
    int quad = l >> 4, m16 = l & 15;
    int n = nt * 16 + m16;
    int k0 = quad * 8 + 2 * jj;
    auto wf = [&](int k) -> float {
      if (k < 20) return W1[(k + 1) * HID + n];
      if (k == 20) return W1[n];       // t row
      if (k == 21) return b1[n];       // bias column (X supplies 1.0)
      return 0.f;
    };
    wu[5120 + e] = pk2(wf(k0), wf(k0 + 1));
  }
  // W2PTF (layer2^T 16x16x16 A-frags): frag f = hk*2+tile; 2 dw/lane
  for (int e = tid; e < 2048; e += 256) {
    int f = e >> 7, rem = e & 127, l = rem >> 1, jj = rem & 1;
    int hk = f >> 1, tile = f & 1;
    int m16 = l & 15;
    int quad = l >> 4;
    int d = tile ? 16 + m16 : m16;
    bool ok = (d < 20);
    int h0 = hk * 16 + quad * 4 + 2 * jj;
    float f0 = ok ? wsc[2048 + h0 * 20 + d] : 0.f;
    float f1 = ok ? wsc[2048 + (h0 + 1) * 20 + d] : 0.f;
    wu[7168 + e] = pk2(f0, f1);
  }
  // PPTF / MPTF (integrand^T A-frags, K=32 layout): tile in {0,1}
  for (int e = tid; e < 512; e += 256) {
    int tile = e >> 8, rem = e & 255, l = rem >> 2, jj = rem & 3;
    int quad = l >> 4, m16 = l & 15;
    int d = tile ? 16 + m16 : m16;
    bool ok = (d < 20);
    int k0 = quad * 8 + 2 * jj;
    float f0 = (ok && k0 < 20) ? wsc[d * 20 + k0] : 0.f;
    float f1 = (ok && k0 + 1 < 20) ? wsc[d * 20 + k0 + 1] : 0.f;
    wu[9216 + e] = pk2(f0, f1);
    float g0 = (ok && k0 < 20) ? wsc[400 + d * 20 + k0] : 0.f;
    float g1 = (ok && k0 + 1 < 20) ? wsc[400 + d * 20 + k0 + 1] : 0.f;
    wu[9728 + e] = pk2(g0, g1);
  }
}

// ================= kernel A: fully-transposed MLP scan, ZERO LDS =================
// Exact r13 structure (82us, best) + ONE change: the layer2 accumulation is
// split into two 4-deep MFMA16K chains per output (u0a/u0b, u1a/u1b, summed
// at the end) instead of one 8-deep chain -- halves the exposed MFMA-latency
// of the longest in-step serial chain, +8 VGPRs (headroom exists at 104).
// r14 lesson: do NOT drop prefetch regs for occupancy -- (256,3) pressure
// makes the compiler sink loads to their use, exposing full memory latency.
// Canaries: FETCH >> 100 MB or WRITE >> 20 MB = spill; LDS_Block_Size must be 0.
__global__ __launch_bounds__(256, 2) void kA(
    const float* __restrict__ states, const float* __restrict__ noises,
    const float* __restrict__ controls, const float* __restrict__ ts,
    const float* __restrict__ wsc, float* __restrict__ zc,
    int nch, int cbase, int crem) {
  const int tid = threadIdx.x;
  const int l = tid & 63;
  const int w = tid >> 6;
  const int quad = l >> 4;
  const int m16 = l & 15;

  const int c = blockIdx.x >> 6;
  const int slab = blockIdx.x & 63;
  const int b0 = slab * 64 + w * 16;
  const int sz = cbase + ((c < crem) ? 1 : 0);
  const int thi = 200 - (c * cbase + ((c < crem) ? c : crem));
  const int tlo = thi - (sz - 1);

  // ---- weight fragments (coalesced loads from prepacked tables) ----
  short8 W1T[8];
#pragma unroll
  for (int nt = 0; nt < 8; ++nt)
    W1T[nt] = *(const short8*)(wsc + 5120 + nt * 256 + l * 4);
  sv4 W2T[16];
#pragma unroll
  for (int f = 0; f < 16; ++f)
    W2T[f] = *(const sv4*)(wsc + 7168 + f * 128 + l * 2);
  const short8 PPT0 = *(const short8*)(wsc + 9216 + l * 4);
  const short8 PPT1 = *(const short8*)(wsc + 9472 + l * 4);
  const short8 MPT0 = *(const short8*)(wsc + 9728 + l * 4);
  const short8 MPT1 = *(const short8*)(wsc + 9984 + l * 4);
  const f32x4 b2Av = *(const f32x4*)(wsc + 1600 + quad * 4);
  const f32x4 b2Bv = *(const f32x4*)(wsc + 1616 + quad * 4);

  // ---- global pointers (16B-aligned per-quad slices) ----
  const int row20 = (b0 + m16) * 20;
  const int qoff = (quad == 0) ? 0 : ((quad == 1) ? 8 : 12);
  const float* gx = states + row20 + qoff;
  const float* gn = noises + row20 + qoff;
  const float* gc = controls + row20 + qoff;

  // ---- scan accumulators (tile0: d=quad*4+reg; tile1: d=16+reg, quad0 only) ----
  f32x4 A1a = {0.f, 0.f, 0.f, 0.f}, A1b = {0.f, 0.f, 0.f, 0.f};
  f32x4 A2a = {0.f, 0.f, 0.f, 0.f}, A2b = {0.f, 0.f, 0.f, 0.f};
  f32x4 La = {0.f, 0.f, 0.f, 0.f}, Lb = {0.f, 0.f, 0.f, 0.f};

  // ---- preload first t (vector + scalar) ----
  float4 xv0, xv1, nv0 = {0, 0, 0, 0}, nv1 = {0, 0, 0, 0};
  float4 cv0 = {0, 0, 0, 0}, cv1 = {0, 0, 0, 0};
  float tval, dtv = 0.f, rsd = 0.f;
  {
    size_t rb = (size_t)thi * (BATCH * 20);
    xv0 = *(const float4*)(gx + rb);
    xv1 = *(const float4*)(gx + rb + 4);
    tval = ts[thi];
    if (thi < 200) {
      nv0 = *(const float4*)(gn + rb); nv1 = *(const float4*)(gn + rb + 4);
      cv0 = *(const float4*)(gc + rb); cv1 = *(const float4*)(gc + rb + 4);
      dtv = wsc[1200 + thi]; rsd = wsc[1400 + thi];
    }
  }

#pragma unroll 1
  for (int t = thi; t >= tlo; --t) {
    float4 xn0, xn1, nn0, nn1, cn0, cn1;
    float tvn, dtn, rsn;
    if (t > tlo) {
      size_t rb = (size_t)(t - 1) * (BATCH * 20);
      xn0 = *(const float4*)(gx + rb); xn1 = *(const float4*)(gx + rb + 4);
      nn0 = *(const float4*)(gn + rb); nn1 = *(const float4*)(gn + rb + 4);
      cn0 = *(const float4*)(gc + rb); cn1 = *(const float4*)(gc + rb + 4);
      tvn = ts[t - 1];
      dtn = wsc[1200 + t - 1]; rsn = wsc[1400 + t - 1];
    }
    const bool has_s = (t < 200);

    // ---- X^T B-fragment (K order: x0..x19, t@20, 1.0@21) ----
    S8U af;
    if (quad <= 1) {
      af.u[0] = pk2(xv0.x, xv0.y); af.u[1] = pk2(xv0.z, xv0.w);
      af.u[2] = pk2(xv1.x, xv1.y); af.u[3] = pk2(xv1.z, xv1.w);
    } else if (quad == 2) {        // loads were x[12..19]
      af.u[0] = pk2(xv1.x, xv1.y); af.u[1] = pk2(xv1.z, xv1.w);
      af.u[2] = pk2(tval, 1.0f);   af.u[3] = 0u;
    } else {
      af.u[0] = af.u[1] = af.u[2] = af.u[3] = 0u;
    }
    const short8 afs = af.s;

    const f32x4 z4 = {0.f, 0.f, 0.f, 0.f};
    // ---- layer1^T: 8 independent MFMAs -> lane holds H^T[16nt+quad*4+reg][m16]
    f32x4 h0 = MFMA32(W1T[0], afs, z4);
    f32x4 h1 = MFMA32(W1T[1], afs, z4);
    f32x4 h2 = MFMA32(W1T[2], afs, z4);
    f32x4 h3 = MFMA32(W1T[3], afs, z4);
    f32x4 h4 = MFMA32(W1T[4], afs, z4);
    f32x4 h5 = MFMA32(W1T[5], afs, z4);
    f32x4 h6 = MFMA32(W1T[6], afs, z4);
    f32x4 h7 = MFMA32(W1T[7], afs, z4);

    // ---- layer2^T: tanh in regs -> 16x16x16 MFMAs; TWO 4-deep chains per
    //      output (a/b) instead of one 8-deep chain ----
    f32x4 u0a = b2Av, u1a = b2Bv;
    f32x4 u0b = z4, u1b = z4;
#define L2STEP(hk, hr, U0, U1)                                          \
    {                                                                   \
      S4U hb;                                                           \
      hb.u[0] = pk2(tanh_fast(hr[0]), tanh_fast(hr[1]));                \
      hb.u[1] = pk2(tanh_fast(hr[2]), tanh_fast(hr[3]));                \
      U0 = MFMA16K(W2T[2 * hk], hb.s, U0);                              \
      U1 = MFMA16K(W2T[2 * hk + 1], hb.s, U1);                          \
    }
    L2STEP(0, h0, u0a, u1a) L2STEP(1, h1, u0b, u1b)
    L2STEP(2, h2, u0a, u1a) L2STEP(3, h3, u0b, u1b)
    L2STEP(4, h4, u0a, u1a) L2STEP(5, h5, u0b, u1b)
    L2STEP(6, h6, u0a, u1a) L2STEP(7, h7, u0b, u1b)
#undef L2STEP
    f32x4 u0 = u0a + u0b;
    f32x4 u1 = u1a + u1b;

    // ---- integrand^T: S^T = Pp.X^T + Mp.Y^T (X frag reused) ----
    f32x4 s0 = z4, s1 = z4;
    if (has_s) {
      S8U yf;
      if (quad <= 1) {
        yf.u[0] = pk2(fmaf(nv0.x, rsd, cv0.x), fmaf(nv0.y, rsd, cv0.y));
        yf.u[1] = pk2(fmaf(nv0.z, rsd, cv0.z), fmaf(nv0.w, rsd, cv0.w));
        yf.u[2] = pk2(fmaf(nv1.x, rsd, cv1.x), fmaf(nv1.y, rsd, cv1.y));
        yf.u[3] = pk2(fmaf(nv1.z, rsd, cv1.z), fmaf(nv1.w, rsd, cv1.w));
      } else if (quad == 2) {
        yf.u[0] = pk2(fmaf(nv1.x, rsd, cv1.x), fmaf(nv1.y, rsd, cv1.y));
        yf.u[1] = pk2(fmaf(nv1.z, rsd, cv1.z), fmaf(nv1.w, rsd, cv1.w));
        yf.u[2] = 0u; yf.u[3] = 0u;
      } else {
        yf.u[0] = yf.u[1] = yf.u[2] = yf.u[3] = 0u;
      }
      f32x4 a0 = MFMA32(PPT0, afs, z4);
      a0 = MFMA32(MPT0, yf.s, a0);
      f32x4 a1 = MFMA32(PPT1, afs, z4);
      a1 = MFMA32(MPT1, yf.s, a1);
      s0 = a0 * dtv;
      s1 = a1 * dtv;
    }

    // ---- scan update ----
    La += s0;
    Lb += s1;
    f32x4 p0 = u0 - La;
    f32x4 p1 = u1 - Lb;
    A2a += p0;
    A2b += p1;
    A1a += p0 * p0;
    A1b += p1 * p1;

    // rotate prefetch (vector + scalar)
    xv0 = xn0; xv1 = xn1;
    nv0 = nn0; nv1 = nn1;
    cv0 = cn0; cv1 = cn1;
    tval = tvn; dtv = dtn; rsd = rsn;
  }

  // ---- epilogue: lane owns batch b0+m16, dims quad*4+reg (+16.. for quad0) ----
  const size_t CH = (size_t)BATCH * DIM;
  float* zA1 = zc;
  float* zA2 = zc + (size_t)nch * CH;
  float* zS = zc + (size_t)2 * nch * CH;
  size_t base = ((size_t)c * BATCH + (b0 + m16)) * 20 + quad * 4;
#pragma unroll
  for (int reg = 0; reg < 4; ++reg) {
    zA1[base + reg] = A1a[reg];
    zA2[base + reg] = A2a[reg];
    zS[base + reg] = La[reg];
  }
  if (quad == 0) {
#pragma unroll
    for (int reg = 0; reg < 4; ++reg) {
      zA1[base + 16 + reg] = A1b[reg];
      zA2[base + 16 + reg] = A2b[reg];
      zS[base + 16 + reg] = Lb[reg];
    }
  }
}

// ================= kernel B: combine chunks =================
__global__ __launch_bounds__(256) void kB(
    const float* __restrict__ states, const float* __restrict__ lw,
    const float* __restrict__ wsc, const float* __restrict__ zc,
    float* __restrict__ out, int nch, int cbase, int crem) {
  __shared__ float sQp[400];
  __shared__ float part[4];
  int tid = threadIdx.x;
  for (int e = tid; e < 400; e += 256) sQp[e] = wsc[800 + e];
  __syncthreads();
  const int u = blockIdx.x * 256 + tid;
  const int b = u / 20;
  const int i = u - b * 20;
  const float* xp = states + ((size_t)NSTEP * BATCH + b) * 20;
  float term = 0.f;
#pragma unroll
  for (int j = 0; j < 20; ++j) term = fmaf(sQp[i * 20 + j], xp[j], term);

  const size_t CH = (size_t)BATCH * DIM;
  float T = 0.f, obj = 0.f;
  for (int c = 0; c < nch; ++c) {
    float A1 = zc[(size_t)c * CH + u];
    float A2 = zc[(size_t)(nch + c) * CH + u];
    float S = zc[(size_t)(2 * nch + c) * CH + u];
    float K = term + T;
    float nc = (float)(cbase + ((c < crem) ? 1 : 0));
    obj += A1 - 2.f * K * A2 + nc * K * K;
    T += S;
  }
  obj *= __expf(lw[b]) * (1.f / ((float)TN * (float)BATCH));
#pragma unroll
  for (int off = 32; off > 0; off >>= 1) obj += __shfl_down(obj, off, 64);
  if ((tid & 63) == 0) part[tid >> 6] = obj;
  __syncthreads();
  if (tid == 0) atomicAdd(out, (part[0] + part[1]) + (part[2] + part[3]));
}

extern "C" void kernel_launch(void* const* d_in, const int* in_sizes, int n_in,
                              void* d_out, int out_size, void* d_ws, size_t ws_size,
                              hipStream_t stream) {
  const float* states = (const float*)d_in[0];
  const float* noises = (const float*)d_in[1];
  const float* controls = (const float*)d_in[2];
  const float* lw = (const float*)d_in[3];
  const float* ts = (const float*)d_in[4];
  const float* sigma = (const float*)d_in[5];
  const float* P = (const float*)d_in[6];
  const float* A = (const float*)d_in[7];
  const float* Q = (const float*)d_in[8];
  const float* W1 = (const float*)d_in[9];
  const float* b1 = (const float*)d_in[10];
  const float* W2 = (const float*)d_in[11];
  const float* b2 = (const float*)d_in[12];
  float* out = (float*)d_out;

  float* wsc = (float*)d_ws;
  float* zc = wsc + 12288;

  // nch=8 -> 512 blocks = exactly 2 blocks/CU = the resident count at this
  // reg budget -> ONE serial round of ~25 steps (r13-proven optimum).
  int nch = 8;
  size_t need = ((size_t)12288 + (size_t)3 * nch * BATCH * DIM) * sizeof(float);
  if (ws_size < need) nch = 4;
  int cbase = TN / nch;
  int crem = TN - cbase * nch;

  (void)hipMemsetAsync(out, 0, sizeof(float), stream);
  hipLaunchKernelGGL(k0_setup, dim3(1), dim3(256), 0, stream,
                     ts, sigma, A, P, Q, W2, b2, W1, b1, wsc);
  hipLaunchKernelGGL(kA, dim3(nch * 64), dim3(256), 0, stream,
                     states, noises, controls, ts, wsc, zc, nch, cbase, crem);
  hipLaunchKernelGGL(kB, dim3((BATCH * DIM) / 256), dim3(256), 0, stream,
                     states, lw, wsc, zc, out, nch, cbase, crem);
}